// Round 1
// baseline (32155.527 us; speedup 1.0000x reference)
//
#include <hip/hip_runtime.h>
#include <math.h>

#define B_    32
#define D_    768
#define H_    12
#define DH_   64
#define NTOK  197
#define NA    210
#define NM    256
#define NRM   201

__device__ __forceinline__ float sigmoidf_(float x){ return 1.f/(1.f+expf(-x)); }
__device__ __forceinline__ float gelu_f(float x){
  float x2 = x*x;
  float f  = 0.7978845608028654f*(x + 0.044715f*x*x2);
  float t  = tanhf(f);
  return 0.5f*x*(1.f+t);
}
__device__ __forceinline__ float gelu_grad(float x){
  float x2 = x*x;
  float f  = 0.7978845608028654f*(x + 0.044715f*x*x2);
  float t  = tanhf(f);
  float fp = 0.7978845608028654f*(1.f + 0.134145f*x2);
  return 0.5f*(1.f+t) + 0.5f*x*(1.f-t*t)*fp;
}

__device__ __forceinline__ float block_reduce_sum(float v, float* sred){
  int tid = threadIdx.x;
  sred[tid] = v; __syncthreads();
  for (int s = 128; s > 0; s >>= 1){ if (tid < s) sred[tid] += sred[tid+s]; __syncthreads(); }
  float r = sred[0]; __syncthreads();
  return r;
}

// ---------------- patch embedding ----------------
__global__ void patch_ln1_k(const float* __restrict__ img, const float* __restrict__ g,
                            const float* __restrict__ bt, float* __restrict__ XP)
{
  int p = blockIdx.x, b = blockIdx.y, tid = threadIdx.x;
  int gy = p / 14, gx = p % 14;
  __shared__ float sred[256];
  float v[3];
  #pragma unroll
  for (int i=0;i<3;i++){
    int pd = tid + i*256;
    int c = pd % 3; int t2 = pd/3; int px = t2 & 15, py = t2 >> 4;
    v[i] = img[((long)b*3 + c)*224*224 + (long)(gy*16+py)*224 + (gx*16+px)];
  }
  float mean = block_reduce_sum(v[0]+v[1]+v[2], sred)*(1.f/768.f);
  float d0=v[0]-mean, d1=v[1]-mean, d2=v[2]-mean;
  float var = block_reduce_sum(d0*d0+d1*d1+d2*d2, sred)*(1.f/768.f);
  float rs = rsqrtf(var+1e-5f);
  float* o = XP + ((long)b*196 + p)*768;
  o[tid]     = d0*rs*g[tid]    +bt[tid];
  o[tid+256] = d1*rs*g[tid+256]+bt[tid+256];
  o[tid+512] = d2*rs*g[tid+512]+bt[tid+512];
}

__device__ __forceinline__ float pe_val(int j, int x, int y){
  int q = j / 192, k = j % 192;
  float om = expf(-(float)k*(9.210340371976184f/191.f));
  float arg = (q < 2 ? (float)x : (float)y) * om;
  return (q & 1) ? cosf(arg) : sinf(arg);
}

__global__ void patch_final_k(const float* __restrict__ XE, const float* __restrict__ g,
                              const float* __restrict__ bt, const float* __restrict__ cls,
                              float* __restrict__ XF)
{
  int t = blockIdx.x, b = blockIdx.y, tid = threadIdx.x;
  float* o = XF + ((long)b*NTOK + t)*768;
  if (t == 0){ for (int i=tid;i<768;i+=256) o[i] = cls[i]; return; }
  int p = t-1, y = p/14, x = p%14;
  __shared__ float sred[256];
  const float* s = XE + ((long)b*196 + p)*768;
  float v0=s[tid], v1=s[tid+256], v2=s[tid+512];
  float mean = block_reduce_sum(v0+v1+v2, sred)*(1.f/768.f);
  float d0=v0-mean, d1=v1-mean, d2=v2-mean;
  float var = block_reduce_sum(d0*d0+d1*d1+d2*d2, sred)*(1.f/768.f);
  float rs = rsqrtf(var+1e-5f);
  o[tid]     = d0*rs*g[tid]    +bt[tid]     + pe_val(tid,     x, y);
  o[tid+256] = d1*rs*g[tid+256]+bt[tid+256] + pe_val(tid+256, x, y);
  o[tid+512] = d2*rs*g[tid+512]+bt[tid+512] + pe_val(tid+512, x, y);
}

// ---------------- generic LN over 768 ----------------
// rows [0,n1): from X;  rows [n1,n2): from extra (shared across batch); rows >= n2: zeros
__global__ void ln_rows_k(const float* __restrict__ X, long xb, int xr,
                          const float* __restrict__ extra,
                          const float* __restrict__ gamma, const float* __restrict__ beta,
                          float* __restrict__ Y, long yb, int yr, int n1, int n2)
{
  __shared__ float sred[256];
  int row = blockIdx.x, b = blockIdx.y, tid = threadIdx.x;
  float* yrow = Y + (long)b*yb + (long)row*yr;
  const float* src = nullptr;
  if (row < n1) src = X + (long)b*xb + (long)row*xr;
  else if (row < n2) src = extra + (long)(row-n1)*768;
  if (!src){ yrow[tid]=0.f; yrow[tid+256]=0.f; yrow[tid+512]=0.f; return; }
  float v0=src[tid], v1=src[tid+256], v2=src[tid+512];
  float mean = block_reduce_sum(v0+v1+v2, sred)*(1.f/768.f);
  float d0=v0-mean, d1=v1-mean, d2=v2-mean;
  float var = block_reduce_sum(d0*d0+d1*d1+d2*d2, sred)*(1.f/768.f);
  float rs = rsqrtf(var+1e-5f);
  yrow[tid]     = d0*rs*gamma[tid]    +beta[tid];
  yrow[tid+256] = d1*rs*gamma[tid+256]+beta[tid+256];
  yrow[tid+512] = d2*rs*gamma[tid+512]+beta[tid+512];
}

// ---------------- generic fp32 GEMM: C[b,m,n] = A[b,m,:]@W + bias + Res ----------------
__global__ void gemm_k(const float* __restrict__ A, long asb, int asr,
                       const float* __restrict__ W, const float* __restrict__ bias,
                       const float* Res, long rsb, int rsr,
                       float* C, long csb, int csr,
                       int M, int N, int K)
{
  __shared__ float As[16][68];
  __shared__ float Bs[16][68];
  int b  = blockIdx.z;
  int m0 = blockIdx.y * 64;
  int n0 = blockIdx.x * 64;
  const float* Ab = A + (long)b*asb;
  float acc[4][4] = {};
  int tid = threadIdx.x;
  int tm = tid >> 4, tn = tid & 15;
  for (int k0 = 0; k0 < K; k0 += 16){
    for (int i = tid; i < 64*16; i += 256){
      int mm = i >> 4, kk = i & 15;
      int m = m0 + mm;
      As[kk][mm] = (m < M) ? Ab[(long)m*asr + k0 + kk] : 0.f;
    }
    for (int i = tid; i < 16*64; i += 256){
      int kk = i >> 6, nn = i & 63;
      int n = n0 + nn;
      Bs[kk][nn] = (n < N) ? W[(long)(k0+kk)*N + n] : 0.f;
    }
    __syncthreads();
    #pragma unroll
    for (int kk = 0; kk < 16; ++kk){
      float a[4], bb[4];
      #pragma unroll
      for (int i=0;i<4;i++) a[i]  = As[kk][tm*4+i];
      #pragma unroll
      for (int j=0;j<4;j++) bb[j] = Bs[kk][tn*4+j];
      #pragma unroll
      for (int i=0;i<4;i++)
        #pragma unroll
        for (int j=0;j<4;j++) acc[i][j] += a[i]*bb[j];
    }
    __syncthreads();
  }
  for (int i=0;i<4;i++){
    int m = m0 + tm*4 + i;
    if (m >= M) continue;
    for (int j=0;j<4;j++){
      int n = n0 + tn*4 + j;
      if (n >= N) continue;
      float v = acc[i][j];
      if (bias) v += bias[n];
      if (Res)  v += Res[(long)b*rsb + (long)m*rsr + n];
      C[(long)b*csb + (long)m*csr + n] = v;
    }
  }
}

// ---------------- windowed attention ----------------
__global__ void win_attn_k(const float* __restrict__ QKV, float* __restrict__ O)
{
  int w = blockIdx.x, h = blockIdx.y, b = blockIdx.z, tid = threadIdx.x;
  __shared__ float sQ[14*64], sK[14*64], sV[14*64], sS[14*16];
  for (int i=tid; i<14*64; i+=256){
    int r=i>>6, d=i&63;
    long base = ((long)b*NA + (w*14+r))*2304 + h*64 + d;
    sQ[i]=QKV[base]; sK[i]=QKV[base+768]; sV[i]=QKV[base+1536];
  }
  __syncthreads();
  if (tid < 196){
    int r = tid/14, u = tid%14;
    float s=0;
    #pragma unroll
    for (int d=0; d<64; ++d) s += sQ[r*64+d]*sK[u*64+d];
    sS[r*16+u] = s*0.125f;
  }
  __syncthreads();
  if (tid < 14){
    float m=-1e30f;
    for (int u=0;u<14;++u) m = fmaxf(m, sS[tid*16+u]);
    float sum=0;
    for (int u=0;u<14;++u){ float e=expf(sS[tid*16+u]-m); sS[tid*16+u]=e; sum+=e; }
    float inv=1.f/sum;
    for (int u=0;u<14;++u) sS[tid*16+u]*=inv;
  }
  __syncthreads();
  for (int i=tid; i<14*64; i+=256){
    int r=i>>6, d=i&63;
    float o=0;
    #pragma unroll
    for (int u=0;u<14;++u) o += sS[r*16+u]*sV[u*64+d];
    O[((long)b*NA + (w*14+r))*768 + h*64 + d] = o;
  }
}

// ---------------- lr projection ----------------
__global__ void lr_k(const float* __restrict__ XN, const float* __restrict__ Wlr,
                     const float* __restrict__ blr, float* __restrict__ LR)
{
  int t = blockIdx.x, b = blockIdx.y, tid = threadIdx.x;
  __shared__ float row[768];
  const float* src = XN + ((long)b*NM + t)*768;
  for (int i=tid;i<768;i+=256) row[i]=src[i];
  __syncthreads();
  if (tid < 192){
    int g = tid>>4, l = tid&15;
    float s=0;
    for (int d=l; d<768; d+=16) s += row[d]*Wlr[d*12+g];
    for (int o=8;o;o>>=1) s += __shfl_down(s, o, 16);
    if (l==0){
      float m = (t < NRM) ? 1.f : 0.f;
      LR[((long)b*NM + t)*12 + g] = sigmoidf_(s + blr[g]) * 0.01f * m;
    }
  }
}

// ---------------- mom/dec (fused chunk-mean + proj + sigmoid) ----------------
__global__ void momdec_k(const float* __restrict__ XN, const float* __restrict__ Wm,
                         const float* __restrict__ bm, const float* __restrict__ Wd,
                         const float* __restrict__ bd, float* __restrict__ MOMv,
                         float* __restrict__ DECv)
{
  int c = blockIdx.x, b = blockIdx.y, tid = threadIdx.x;
  __shared__ float xm[768];
  for (int col=tid; col<768; col+=256){
    float s=0;
    const float* base = XN + ((long)b*NM + c*64)*768 + col;
    for (int ci=0; ci<64; ++ci) s += base[(long)ci*768];
    xm[col] = s*(1.f/64.f);
  }
  __syncthreads();
  if (tid < 192){
    int g = tid>>3, l = tid&7;
    const float* W = (g<12)? Wm : Wd;
    int j = (g<12)? g : g-12;
    float s=0;
    for (int d=l; d<768; d+=8) s += xm[d]*W[d*12+j];
    for (int o=4;o;o>>=1) s += __shfl_down(s, o, 8);
    if (l==0){
      float val = sigmoidf_(s + ((g<12)?bm[j]:bd[j]));
      if (g<12) MOMv[(b*4+c)*12+j] = val; else DECv[(b*4+c)*12+j] = val;
    }
  }
}

// ---------------- neural memory scan ----------------
__device__ void specnorm_update(float* G, float* S, float* M, float momc, float decc,
                                float* sVec, float* sU, float* sred)
{
  int tid = threadIdx.x;
  float loc=0;
  for (int i=tid;i<4096;i+=256){ float g=G[i]; loc += g*g; }
  float fro = block_reduce_sum(loc, sred);
  float cs = fminf(1.f, 1.f/(sqrtf(fro)+1e-8f));
  for (int i=tid;i<4096;i+=256) G[i]*=cs;
  if (tid<64) sVec[tid]=0.125f;
  __syncthreads();
  for (int it=0; it<3; ++it){
    float uval=0;
    if (tid<64){ float s=0; for (int c2=0;c2<64;++c2) s+=G[tid*64+c2]*sVec[c2]; uval=s; }
    float nu = sqrtf(block_reduce_sum(tid<64? uval*uval:0.f, sred))+1e-8f;
    if (tid<64) sU[tid]=uval/nu;
    __syncthreads();
    float vval=0;
    if (tid<64){ float s=0; for (int r=0;r<64;++r) s+=G[r*64+tid]*sU[r]; vval=s; }
    float nv = sqrtf(block_reduce_sum(tid<64? vval*vval:0.f, sred))+1e-8f;
    if (tid<64) sVec[tid]=vval/nv;
    __syncthreads();
  }
  float tpart=0;
  if (tid<64){ float s=0; for (int c2=0;c2<64;++c2) s+=G[tid*64+c2]*sVec[c2]; tpart=sU[tid]*s; }
  float sigma = block_reduce_sum(tid<64? tpart:0.f, sred);
  float inv = 1.f/(sigma+1e-8f);
  for (int i=tid;i<4096;i+=256){
    float sm = -G[i]*inv;
    float Sv = momc*S[i] + sm;
    S[i]=Sv;
    M[i] = (1.f-decc)*M[i] + Sv;
  }
  __syncthreads();
}

__global__ __launch_bounds__(256,1) void memscan_k(
    const float* __restrict__ Qm, const float* __restrict__ Km, const float* __restrict__ Vm,
    const float* __restrict__ LR, const float* __restrict__ MOMv, const float* __restrict__ DECv,
    const float* __restrict__ M1i, const float* __restrict__ M2i,
    float* __restrict__ OUT)
{
  int h = blockIdx.x, b = blockIdx.y, tid = threadIdx.x;
  __shared__ float sM1[4096], sM2[4096], sS1[4096], sS2[4096];
  __shared__ float sK[4096], sA[4096], sG[4096], sD[4096], sG2[4096];
  __shared__ float sLr[64], sVec[64], sU[64], sred[256];

  for (int i=tid; i<4096; i+=256){ sM1[i]=M1i[i]; sM2[i]=M2i[i]; sS1[i]=0.f; sS2[i]=0.f; }
  __syncthreads();

  for (int c=0;c<4;++c){
    for (int i=tid;i<4096;i+=256){
      int ci=i>>6, d=i&63;
      sK[i] = Km[((long)b*NM + c*64+ci)*768 + h*64 + d];
    }
    if (tid<64) sLr[tid] = LR[((long)b*NM + c*64+tid)*12 + h];
    float momc = MOMv[(b*4+c)*12+h];
    float decc = DECv[(b*4+c)*12+h];
    __syncthreads();

    // h1 = K @ M1
    for (int i=tid;i<4096;i+=256){
      int ci=i>>6, e=i&63;
      float s=0;
      for (int d2=0;d2<64;++d2) s += sK[ci*64+d2]*sM1[d2*64+e];
      sA[i]=s;
    }
    __syncthreads();
    for (int i=tid;i<4096;i+=256) sG[i] = gelu_f(sA[i]);
    __syncthreads();
    // pred = G @ M2 ; dpred = lr*(pred - v)
    for (int i=tid;i<4096;i+=256){
      int ci=i>>6, e=i&63;
      float s=0;
      for (int d2=0;d2<64;++d2) s += sG[ci*64+d2]*sM2[d2*64+e];
      float vv = Vm[((long)b*NM + c*64+ci)*768 + h*64 + e];
      sD[i] = sLr[ci]*(s - vv);
    }
    __syncthreads();
    // g2 = G^T @ D
    for (int i=tid;i<4096;i+=256){
      int d2=i>>6, e=i&63;
      float s=0;
      for (int ci=0;ci<64;++ci) s += sG[ci*64+d2]*sD[ci*64+e];
      sG2[i]=s;
    }
    __syncthreads();
    // dg = (D @ M2^T) * gelu'(h1)  (overwrite sA)
    for (int i=tid;i<4096;i+=256){
      int ci=i>>6, d2=i&63;
      float s=0;
      for (int e=0;e<64;++e) s += sD[ci*64+e]*sM2[d2*64+e];
      sA[i] = s * gelu_grad(sA[i]);
    }
    __syncthreads();
    // g1 = K^T @ dg  (overwrite sG)
    for (int i=tid;i<4096;i+=256){
      int d2=i>>6, e=i&63;
      float s=0;
      for (int ci=0;ci<64;++ci) s += sK[ci*64+d2]*sA[ci*64+e];
      sG[i]=s;
    }
    __syncthreads();

    specnorm_update(sG,  sS1, sM1, momc, decc, sVec, sU, sred);
    specnorm_update(sG2, sS2, sM2, momc, decc, sVec, sU, sred);

    // out = gelu(q @ M1) @ M2
    for (int i=tid;i<4096;i+=256){
      int ci=i>>6, d2=i&63;
      sD[i] = Qm[((long)b*NM + c*64+ci)*768 + h*64 + d2];
    }
    __syncthreads();
    for (int i=tid;i<4096;i+=256){
      int ci=i>>6, e=i&63;
      float s=0;
      for (int d2=0;d2<64;++d2) s += sD[ci*64+d2]*sM1[d2*64+e];
      sA[i] = gelu_f(s);
    }
    __syncthreads();
    for (int i=tid;i<4096;i+=256){
      int ci=i>>6, e=i&63;
      float s=0;
      for (int d2=0;d2<64;++d2) s += sA[ci*64+d2]*sM2[d2*64+e];
      OUT[((long)b*NM + c*64+ci)*768 + h*64 + e] = s;
    }
    __syncthreads();
  }
}

// ---------------- launch ----------------
extern "C" void kernel_launch(void* const* d_in, const int* in_sizes, int n_in,
                              void* d_out, int out_size, void* d_ws, size_t ws_size,
                              hipStream_t stream)
{
  const float* img = (const float*)d_in[0];
  const float* p1s = (const float*)d_in[1];
  const float* p1b = (const float*)d_in[2];
  const float* Wp  = (const float*)d_in[3];
  const float* bp  = (const float*)d_in[4];
  const float* p2s = (const float*)d_in[5];
  const float* p2b = (const float*)d_in[6];
  const float* cls = (const float*)d_in[7];
  const float* las = (const float*)d_in[8];
  const float* lab = (const float*)d_in[9];
  const float* Wqkv= (const float*)d_in[10];
  const float* Wao = (const float*)d_in[11];
  const float* regs= (const float*)d_in[12];
  const float* lms = (const float*)d_in[13];
  const float* lmb = (const float*)d_in[14];
  const float* Wmq = (const float*)d_in[15];
  const float* Wmk = (const float*)d_in[16];
  const float* Wmv = (const float*)d_in[17];
  const float* Wmo = (const float*)d_in[18];
  const float* Wlr = (const float*)d_in[19];
  const float* blr = (const float*)d_in[20];
  const float* Wmom= (const float*)d_in[21];
  const float* bmom= (const float*)d_in[22];
  const float* Wdec= (const float*)d_in[23];
  const float* bdec= (const float*)d_in[24];
  const float* M1i = (const float*)d_in[25];
  const float* M2i = (const float*)d_in[26];
  const float* fls = (const float*)d_in[27];
  const float* flb = (const float*)d_in[28];
  const float* Wh  = (const float*)d_in[29];
  const float* bh  = (const float*)d_in[30];
  float* out = (float*)d_out;

  float* ws = (float*)d_ws;
  size_t off = 0;
  auto alloc = [&](size_t n){ float* p = ws + off; off += n; return p; };
  float* XF   = alloc((size_t)B_*NTOK*768);
  float* XN_A = alloc((size_t)B_*NA*768);
  float* QKV  = alloc((size_t)B_*NA*2304);
  float* ATT_O= alloc((size_t)B_*NA*768);
  float* XN_M = alloc((size_t)B_*NM*768);
  float* QM   = alloc((size_t)B_*NM*768);
  float* KM   = alloc((size_t)B_*NM*768);
  float* VM   = alloc((size_t)B_*NM*768);
  float* LRb  = alloc((size_t)B_*NM*12);
  float* MOMb = alloc((size_t)B_*4*12);
  float* DECb = alloc((size_t)B_*4*12);
  float* MEMO = alloc((size_t)B_*NM*768);
  float* XHEAD= alloc((size_t)B_*768);
  float* XP = QKV;   // patch temps alias later buffers (disjoint lifetime)
  float* XE = XN_M;

  // patch embed
  patch_ln1_k<<<dim3(196,B_),256,0,stream>>>(img, p1s, p1b, XP);
  gemm_k<<<dim3(12,98,1),256,0,stream>>>(XP,0,768, Wp, bp, nullptr,0,0, XE,0,768, 6272,768,768);
  patch_final_k<<<dim3(197,B_),256,0,stream>>>(XE, p2s, p2b, cls, XF);

  for (int l=0; l<12; ++l){
    const float* Wqkv_l = Wqkv + (long)l*768*2304;
    const float* Wao_l  = Wao  + (long)l*768*768;
    const float* Wmq_l  = Wmq  + (long)l*768*768;
    const float* Wmk_l  = Wmk  + (long)l*768*768;
    const float* Wmv_l  = Wmv  + (long)l*768*768;
    const float* Wmo_l  = Wmo  + (long)l*768*768;
    const float* Wlr_l  = Wlr  + (long)l*768*12;
    const float* blr_l  = blr  + (long)l*12;
    const float* Wmom_l = Wmom + (long)l*768*12;
    const float* bmom_l = bmom + (long)l*12;
    const float* Wdec_l = Wdec + (long)l*768*12;
    const float* bdec_l = bdec + (long)l*12;

    // windowed attention
    ln_rows_k<<<dim3(NA,B_),256,0,stream>>>(XF,(long)NTOK*768,768, nullptr,
                                            las+l*768, lab+l*768,
                                            XN_A,(long)NA*768,768, NTOK, NTOK);
    gemm_k<<<dim3(36,105,1),256,0,stream>>>(XN_A,0,768, Wqkv_l, nullptr, nullptr,0,0,
                                            QKV,0,2304, B_*NA,2304,768);
    win_attn_k<<<dim3(15,12,B_),256,0,stream>>>(QKV, ATT_O);
    gemm_k<<<dim3(12,4,B_),256,0,stream>>>(ATT_O,(long)NA*768,768, Wao_l, nullptr,
                                           XF,(long)NTOK*768,768,
                                           XF,(long)NTOK*768,768, NTOK,768,768);

    // neural memory
    ln_rows_k<<<dim3(NM,B_),256,0,stream>>>(XF,(long)NTOK*768,768, regs+(long)l*4*768,
                                            lms+l*768, lmb+l*768,
                                            XN_M,(long)NM*768,768, NTOK, NRM);
    gemm_k<<<dim3(12,128,1),256,0,stream>>>(XN_M,0,768, Wmq_l, nullptr, nullptr,0,0,
                                            QM,0,768, B_*NM,768,768);
    gemm_k<<<dim3(12,128,1),256,0,stream>>>(XN_M,0,768, Wmk_l, nullptr, nullptr,0,0,
                                            KM,0,768, B_*NM,768,768);
    gemm_k<<<dim3(12,128,1),256,0,stream>>>(XN_M,0,768, Wmv_l, nullptr, nullptr,0,0,
                                            VM,0,768, B_*NM,768,768);
    lr_k<<<dim3(NM,B_),256,0,stream>>>(XN_M, Wlr_l, blr_l, LRb);
    momdec_k<<<dim3(4,B_),256,0,stream>>>(XN_M, Wmom_l, bmom_l, Wdec_l, bdec_l, MOMb, DECb);
    memscan_k<<<dim3(12,B_),256,0,stream>>>(QM, KM, VM, LRb, MOMb, DECb,
                                            M1i+(long)l*4096, M2i+(long)l*4096, MEMO);
    gemm_k<<<dim3(12,4,B_),256,0,stream>>>(MEMO,(long)NM*768,768, Wmo_l, nullptr,
                                           XF,(long)NTOK*768,768,
                                           XF,(long)NTOK*768,768, NTOK,768,768);
  }

  // final LN (row 0 only) + head
  ln_rows_k<<<dim3(1,B_),256,0,stream>>>(XF,(long)NTOK*768,768, nullptr, fls, flb,
                                         XHEAD,768,768, 1, 1);
  gemm_k<<<dim3(16,1,1),256,0,stream>>>(XHEAD,0,768, Wh, bh, nullptr,0,0,
                                        out,0,1000, 32,1000,768);
}

// Round 3
// 18997.015 us; speedup vs baseline: 1.6927x; 1.6927x over previous
//
#include <hip/hip_runtime.h>
#include <math.h>

#define B_    32
#define D_    768
#define H_    12
#define DH_   64
#define NTOK  197
#define NA    210
#define NM    256
#define NRM   201

typedef float f4_t __attribute__((ext_vector_type(4)));
typedef short bf16x8 __attribute__((ext_vector_type(8)));

__device__ __forceinline__ unsigned short f2bf(float x){
  unsigned u = __builtin_bit_cast(unsigned, x);
  unsigned r = (u + 0x7FFFu + ((u >> 16) & 1u)) >> 16;
  return (unsigned short)r;
}

__device__ __forceinline__ float sigmoidf_(float x){ return 1.f/(1.f+expf(-x)); }
__device__ __forceinline__ float gelu_f(float x){
  float x2 = x*x;
  float f  = 0.7978845608028654f*(x + 0.044715f*x*x2);
  float t  = tanhf(f);
  return 0.5f*x*(1.f+t);
}
__device__ __forceinline__ float gelu_grad(float x){
  float x2 = x*x;
  float f  = 0.7978845608028654f*(x + 0.044715f*x*x2);
  float t  = tanhf(f);
  float fp = 0.7978845608028654f*(1.f + 0.134145f*x2);
  return 0.5f*(1.f+t) + 0.5f*x*(1.f-t*t)*fp;
}

__device__ __forceinline__ float block_reduce_sum(float v, float* sred){
  int tid = threadIdx.x;
  sred[tid] = v; __syncthreads();
  for (int s = 128; s > 0; s >>= 1){ if (tid < s) sred[tid] += sred[tid+s]; __syncthreads(); }
  float r = sred[0]; __syncthreads();
  return r;
}

// ---------------- patch embedding ----------------
__global__ void patch_ln1_k(const float* __restrict__ img, const float* __restrict__ g,
                            const float* __restrict__ bt, float* __restrict__ XP)
{
  int p = blockIdx.x, b = blockIdx.y, tid = threadIdx.x;
  int gy = p / 14, gx = p % 14;
  __shared__ float sred[256];
  float v[3];
  #pragma unroll
  for (int i=0;i<3;i++){
    int pd = tid + i*256;
    int c = pd % 3; int t2 = pd/3; int px = t2 & 15, py = t2 >> 4;
    v[i] = img[((long)b*3 + c)*224*224 + (long)(gy*16+py)*224 + (gx*16+px)];
  }
  float mean = block_reduce_sum(v[0]+v[1]+v[2], sred)*(1.f/768.f);
  float d0=v[0]-mean, d1=v[1]-mean, d2=v[2]-mean;
  float var = block_reduce_sum(d0*d0+d1*d1+d2*d2, sred)*(1.f/768.f);
  float rs = rsqrtf(var+1e-5f);
  float* o = XP + ((long)b*196 + p)*768;
  o[tid]     = d0*rs*g[tid]    +bt[tid];
  o[tid+256] = d1*rs*g[tid+256]+bt[tid+256];
  o[tid+512] = d2*rs*g[tid+512]+bt[tid+512];
}

__device__ __forceinline__ float pe_val(int j, int x, int y){
  int q = j / 192, k = j % 192;
  float om = expf(-(float)k*(9.210340371976184f/191.f));
  float arg = (q < 2 ? (float)x : (float)y) * om;
  return (q & 1) ? cosf(arg) : sinf(arg);
}

__global__ void patch_final_k(const float* __restrict__ XE, const float* __restrict__ g,
                              const float* __restrict__ bt, const float* __restrict__ cls,
                              float* __restrict__ XF)
{
  int t = blockIdx.x, b = blockIdx.y, tid = threadIdx.x;
  float* o = XF + ((long)b*NTOK + t)*768;
  if (t == 0){ for (int i=tid;i<768;i+=256) o[i] = cls[i]; return; }
  int p = t-1, y = p/14, x = p%14;
  __shared__ float sred[256];
  const float* s = XE + ((long)b*196 + p)*768;
  float v0=s[tid], v1=s[tid+256], v2=s[tid+512];
  float mean = block_reduce_sum(v0+v1+v2, sred)*(1.f/768.f);
  float d0=v0-mean, d1=v1-mean, d2=v2-mean;
  float var = block_reduce_sum(d0*d0+d1*d1+d2*d2, sred)*(1.f/768.f);
  float rs = rsqrtf(var+1e-5f);
  o[tid]     = d0*rs*g[tid]    +bt[tid]     + pe_val(tid,     x, y);
  o[tid+256] = d1*rs*g[tid+256]+bt[tid+256] + pe_val(tid+256, x, y);
  o[tid+512] = d2*rs*g[tid+512]+bt[tid+512] + pe_val(tid+512, x, y);
}

// ---------------- generic LN over 768 ----------------
__global__ void ln_rows_k(const float* __restrict__ X, long xb, int xr,
                          const float* __restrict__ extra,
                          const float* __restrict__ gamma, const float* __restrict__ beta,
                          float* __restrict__ Y, long yb, int yr, int n1, int n2)
{
  __shared__ float sred[256];
  int row = blockIdx.x, b = blockIdx.y, tid = threadIdx.x;
  float* yrow = Y + (long)b*yb + (long)row*yr;
  const float* src = nullptr;
  if (row < n1) src = X + (long)b*xb + (long)row*xr;
  else if (row < n2) src = extra + (long)(row-n1)*768;
  if (!src){ yrow[tid]=0.f; yrow[tid+256]=0.f; yrow[tid+512]=0.f; return; }
  float v0=src[tid], v1=src[tid+256], v2=src[tid+512];
  float mean = block_reduce_sum(v0+v1+v2, sred)*(1.f/768.f);
  float d0=v0-mean, d1=v1-mean, d2=v2-mean;
  float var = block_reduce_sum(d0*d0+d1*d1+d2*d2, sred)*(1.f/768.f);
  float rs = rsqrtf(var+1e-5f);
  yrow[tid]     = d0*rs*gamma[tid]    +beta[tid];
  yrow[tid+256] = d1*rs*gamma[tid+256]+beta[tid+256];
  yrow[tid+512] = d2*rs*gamma[tid+512]+beta[tid+512];
}

// ---------------- fp32 GEMM (head only) ----------------
__global__ void gemm_k(const float* __restrict__ A, long asb, int asr,
                       const float* __restrict__ W, const float* __restrict__ bias,
                       const float* Res, long rsb, int rsr,
                       float* C, long csb, int csr,
                       int M, int N, int K)
{
  __shared__ float As[16][68];
  __shared__ float Bs[16][68];
  int b  = blockIdx.z;
  int m0 = blockIdx.y * 64;
  int n0 = blockIdx.x * 64;
  const float* Ab = A + (long)b*asb;
  float acc[4][4] = {};
  int tid = threadIdx.x;
  int tm = tid >> 4, tn = tid & 15;
  for (int k0 = 0; k0 < K; k0 += 16){
    for (int i = tid; i < 64*16; i += 256){
      int mm = i >> 4, kk = i & 15;
      int m = m0 + mm;
      As[kk][mm] = (m < M) ? Ab[(long)m*asr + k0 + kk] : 0.f;
    }
    for (int i = tid; i < 16*64; i += 256){
      int kk = i >> 6, nn = i & 63;
      int n = n0 + nn;
      Bs[kk][nn] = (n < N) ? W[(long)(k0+kk)*N + n] : 0.f;
    }
    __syncthreads();
    #pragma unroll
    for (int kk = 0; kk < 16; ++kk){
      float a[4], bb[4];
      #pragma unroll
      for (int i=0;i<4;i++) a[i]  = As[kk][tm*4+i];
      #pragma unroll
      for (int j=0;j<4;j++) bb[j] = Bs[kk][tn*4+j];
      #pragma unroll
      for (int i=0;i<4;i++)
        #pragma unroll
        for (int j=0;j<4;j++) acc[i][j] += a[i]*bb[j];
    }
    __syncthreads();
  }
  for (int i=0;i<4;i++){
    int m = m0 + tm*4 + i;
    if (m >= M) continue;
    for (int j=0;j<4;j++){
      int n = n0 + tn*4 + j;
      if (n >= N) continue;
      float v = acc[i][j];
      if (bias) v += bias[n];
      if (Res)  v += Res[(long)b*rsb + (long)m*rsr + n];
      C[(long)b*csb + (long)m*csr + n] = v;
    }
  }
}

// ---------------- bf16 MFMA GEMM: C = A @ W (+bias) (+Res), fp32 in/out ----------------
// 128x128 tile, 4 waves (2x2 of 64x64), BK=32, K multiple of 32, N multiple of 128.
__global__ __launch_bounds__(256) void gemm_bf16_k(
    const float* __restrict__ A, long asb, int lda,
    const float* __restrict__ W, int ldw,
    const float* __restrict__ bias,
    const float* Res, long rsb, int rsr,
    float* C, long csb, int csr,
    int M, int N, int K)
{
  __shared__ unsigned short As[128*40];
  __shared__ unsigned short Bs[128*40];
  int b  = blockIdx.z;
  int m0 = blockIdx.y * 128;
  int n0 = blockIdx.x * 128;
  const float* Ab = A + (long)b*asb;
  int tid = threadIdx.x;
  int lane = tid & 63;
  int w_ = tid >> 6;
  int wm = (w_ >> 1) * 64, wn = (w_ & 1) * 64;
  int fr = lane & 15, fk = (lane >> 4) * 8;

  f4_t acc[4][4] = {};

  for (int k0 = 0; k0 < K; k0 += 32){
    #pragma unroll
    for (int e = 0; e < 16; ++e){
      int idx = e*256 + tid;
      int mm = idx >> 5, kk = idx & 31;
      int m = m0 + mm;
      float a = (m < M) ? Ab[(long)m*lda + k0 + kk] : 0.f;
      As[mm*40 + kk] = f2bf(a);
    }
    #pragma unroll
    for (int e = 0; e < 16; ++e){
      int idx = e*256 + tid;
      int kk = idx >> 7, nn = idx & 127;
      float w = W[(long)(k0+kk)*ldw + n0 + nn];
      Bs[nn*40 + kk] = f2bf(w);
    }
    __syncthreads();
    bf16x8 af[4], bfv[4];
    #pragma unroll
    for (int mf = 0; mf < 4; ++mf)
      af[mf] = *reinterpret_cast<const bf16x8*>(&As[(wm + mf*16 + fr)*40 + fk]);
    #pragma unroll
    for (int nf = 0; nf < 4; ++nf)
      bfv[nf] = *reinterpret_cast<const bf16x8*>(&Bs[(wn + nf*16 + fr)*40 + fk]);
    #pragma unroll
    for (int mf = 0; mf < 4; ++mf)
      #pragma unroll
      for (int nf = 0; nf < 4; ++nf)
        acc[mf][nf] = __builtin_amdgcn_mfma_f32_16x16x32_bf16(af[mf], bfv[nf], acc[mf][nf], 0, 0, 0);
    __syncthreads();
  }

  int cr = (lane >> 4) * 4;
  int cc = lane & 15;
  #pragma unroll
  for (int mf = 0; mf < 4; ++mf){
    #pragma unroll
    for (int nf = 0; nf < 4; ++nf){
      #pragma unroll
      for (int j = 0; j < 4; ++j){
        int m = m0 + wm + mf*16 + cr + j;
        int n = n0 + wn + nf*16 + cc;
        if (m < M && n < N){
          float v = acc[mf][nf][j];
          if (bias) v += bias[n];
          if (Res)  v += Res[(long)b*rsb + (long)m*rsr + n];
          C[(long)b*csb + (long)m*csr + n] = v;
        }
      }
    }
  }
}

// ---------------- windowed attention ----------------
__global__ void win_attn_k(const float* __restrict__ QKV, float* __restrict__ O)
{
  int w = blockIdx.x, h = blockIdx.y, b = blockIdx.z, tid = threadIdx.x;
  __shared__ float sQ[14*64], sK[14*64], sV[14*64], sS[14*16];
  for (int i=tid; i<14*64; i+=256){
    int r=i>>6, d=i&63;
    long base = ((long)b*NA + (w*14+r))*2304 + h*64 + d;
    sQ[i]=QKV[base]; sK[i]=QKV[base+768]; sV[i]=QKV[base+1536];
  }
  __syncthreads();
  if (tid < 196){
    int r = tid/14, u = tid%14;
    float s=0;
    #pragma unroll
    for (int d=0; d<64; ++d) s += sQ[r*64+d]*sK[u*64+d];
    sS[r*16+u] = s*0.125f;
  }
  __syncthreads();
  if (tid < 14){
    float m=-1e30f;
    for (int u=0;u<14;++u) m = fmaxf(m, sS[tid*16+u]);
    float sum=0;
    for (int u=0;u<14;++u){ float e=expf(sS[tid*16+u]-m); sS[tid*16+u]=e; sum+=e; }
    float inv=1.f/sum;
    for (int u=0;u<14;++u) sS[tid*16+u]*=inv;
  }
  __syncthreads();
  for (int i=tid; i<14*64; i+=256){
    int r=i>>6, d=i&63;
    float o=0;
    #pragma unroll
    for (int u=0;u<14;++u) o += sS[r*16+u]*sV[u*64+d];
    O[((long)b*NA + (w*14+r))*768 + h*64 + d] = o;
  }
}

// ---------------- lr projection ----------------
__global__ void lr_k(const float* __restrict__ XN, const float* __restrict__ Wlr,
                     const float* __restrict__ blr, float* __restrict__ LR)
{
  int t = blockIdx.x, b = blockIdx.y, tid = threadIdx.x;
  __shared__ float row[768];
  const float* src = XN + ((long)b*NM + t)*768;
  for (int i=tid;i<768;i+=256) row[i]=src[i];
  __syncthreads();
  if (tid < 192){
    int g = tid>>4, l = tid&15;
    float s=0;
    for (int d=l; d<768; d+=16) s += row[d]*Wlr[d*12+g];
    for (int o=8;o;o>>=1) s += __shfl_down(s, o, 16);
    if (l==0){
      float m = (t < NRM) ? 1.f : 0.f;
      LR[((long)b*NM + t)*12 + g] = sigmoidf_(s + blr[g]) * 0.01f * m;
    }
  }
}

// ---------------- mom/dec ----------------
__global__ void momdec_k(const float* __restrict__ XN, const float* __restrict__ Wm,
                         const float* __restrict__ bm, const float* __restrict__ Wd,
                         const float* __restrict__ bd, float* __restrict__ MOMv,
                         float* __restrict__ DECv)
{
  int c = blockIdx.x, b = blockIdx.y, tid = threadIdx.x;
  __shared__ float xm[768];
  for (int col=tid; col<768; col+=256){
    float s=0;
    const float* base = XN + ((long)b*NM + c*64)*768 + col;
    for (int ci=0; ci<64; ++ci) s += base[(long)ci*768];
    xm[col] = s*(1.f/64.f);
  }
  __syncthreads();
  if (tid < 192){
    int g = tid>>3, l = tid&7;
    const float* W = (g<12)? Wm : Wd;
    int j = (g<12)? g : g-12;
    float s=0;
    for (int d=l; d<768; d+=8) s += xm[d]*W[d*12+j];
    for (int o=4;o;o>>=1) s += __shfl_down(s, o, 8);
    if (l==0){
      float val = sigmoidf_(s + ((g<12)?bm[j]:bd[j]));
      if (g<12) MOMv[(b*4+c)*12+j] = val; else DECv[(b*4+c)*12+j] = val;
    }
  }
}

// ---------------- neural memory scan (v2: padded strides + f4 register tiles) ----------------
// Layout conventions:
//   stride-65 buffers (scalar/broadcast reads, conflict-free): sK, sG
//   stride-64 buffers (float4 row reads):                      sM1, sM2, sM2T, sD, sGP
__device__ void specnorm_update(float* G /*65*/, float* S /*64*/, float* M /*64*/,
                                float momc, float decc,
                                float* sVec, float* sU, float* sred)
{
  int tid = threadIdx.x;
  float loc = 0;
  for (int i = tid; i < 4096; i += 256){ float g = G[(i>>6)*65 + (i&63)]; loc += g*g; }
  float fro = block_reduce_sum(loc, sred);
  float cs = fminf(1.f, 1.f/(sqrtf(fro)+1e-8f));
  for (int i = tid; i < 4096; i += 256) G[(i>>6)*65 + (i&63)] *= cs;
  if (tid < 64) sVec[tid] = 0.125f;
  __syncthreads();
  int r = tid >> 2, p = tid & 3;
  for (int it = 0; it < 3; ++it){
    float s = 0;
    #pragma unroll 4
    for (int k = 0; k < 16; ++k){ int c = p*16 + k; s += G[r*65+c]*sVec[c]; }
    s += __shfl_down(s, 2, 4);
    s += __shfl_down(s, 1, 4);
    float uval = (p==0) ? s : 0.f;
    float nu = sqrtf(block_reduce_sum(uval*uval, sred)) + 1e-8f;
    if (p==0) sU[r] = s/nu;
    __syncthreads();
    float sv = 0;
    #pragma unroll 4
    for (int k = 0; k < 16; ++k){ int rr = p*16 + k; sv += G[rr*65+r]*sU[rr]; }
    sv += __shfl_down(sv, 2, 4);
    sv += __shfl_down(sv, 1, 4);
    float vval = (p==0) ? sv : 0.f;
    float nv = sqrtf(block_reduce_sum(vval*vval, sred)) + 1e-8f;
    if (p==0) sVec[r] = sv/nv;
    __syncthreads();
  }
  float sp = 0;
  #pragma unroll 4
  for (int k = 0; k < 16; ++k){ int c = p*16 + k; sp += G[r*65+c]*sVec[c]; }
  float sigma = block_reduce_sum(sp * sU[r], sred);
  float inv = 1.f/(sigma + 1e-8f);
  for (int i = tid; i < 4096; i += 256){
    float sm = -G[(i>>6)*65 + (i&63)]*inv;
    float Sv = momc*S[i] + sm;
    S[i] = Sv;
    M[i] = (1.f - decc)*M[i] + Sv;
  }
  __syncthreads();
}

__global__ __launch_bounds__(256,1) void memscan_k(
    const float* __restrict__ Qm, const float* __restrict__ Km, const float* __restrict__ Vm,
    const float* __restrict__ LR, const float* __restrict__ MOMv, const float* __restrict__ DECv,
    const float* __restrict__ M1i, const float* __restrict__ M2i,
    float* __restrict__ OUT)
{
  int h = blockIdx.x, b = blockIdx.y, tid = threadIdx.x;
  __shared__ float sM1[4096], sM2[4096], sM2T[4096], sS1[4096], sS2[4096];
  __shared__ float sD[4096], sGP[4096];
  __shared__ float sK[4160], sG[4160];
  __shared__ float sU[64], sVec[64], sLr[64], sred[256];

  for (int i=tid; i<4096; i+=256){ sM1[i]=M1i[i]; sM2[i]=M2i[i]; sS1[i]=0.f; sS2[i]=0.f; }
  __syncthreads();

  int cg = tid >> 4, eq = tid & 15;

  for (int c=0;c<4;++c){
    // ---- stage K (stride 65), lr, and M2T (pre-update M2 transposed) ----
    for (int i=tid; i<1024; i+=256){
      int ci = i >> 4, q = i & 15;
      f4_t kv = *reinterpret_cast<const f4_t*>(&Km[((long)b*NM + c*64+ci)*768 + h*64 + q*4]);
      #pragma unroll
      for (int k=0;k<4;++k) sK[ci*65 + q*4 + k] = kv[k];
    }
    if (tid < 64) sLr[tid] = LR[((long)b*NM + c*64+tid)*12 + h];
    for (int i=tid; i<4096; i+=256){
      int rr = i >> 6, cc = i & 63;
      sM2T[cc*64 + rr] = sM2[i];
    }
    float momc = MOMv[(b*4+c)*12+h];
    float decc = DECv[(b*4+c)*12+h];
    __syncthreads();

    // ---- h1 = K @ M1 ; G = gelu(h1) (65), GP = gelu'(h1) (64) ----
    {
      f4_t acc[4] = {};
      #pragma unroll 4
      for (int d=0; d<64; ++d){
        f4_t bv = *reinterpret_cast<const f4_t*>(&sM1[d*64 + eq*4]);
        #pragma unroll
        for (int j=0;j<4;++j) acc[j] += sK[(cg*4+j)*65 + d] * bv;
      }
      #pragma unroll
      for (int j=0;j<4;++j){
        int ci = cg*4+j;
        f4_t gp;
        #pragma unroll
        for (int k=0;k<4;++k){
          float hv = acc[j][k];
          gp[k] = gelu_grad(hv);
          sG[ci*65 + eq*4 + k] = gelu_f(hv);
        }
        *reinterpret_cast<f4_t*>(&sGP[ci*64 + eq*4]) = gp;
      }
    }
    __syncthreads();

    // ---- pred = G @ M2 ; D = lr*(pred - V) (64) ----
    {
      f4_t acc[4] = {};
      #pragma unroll 4
      for (int d=0; d<64; ++d){
        f4_t bv = *reinterpret_cast<const f4_t*>(&sM2[d*64 + eq*4]);
        #pragma unroll
        for (int j=0;j<4;++j) acc[j] += sG[(cg*4+j)*65 + d] * bv;
      }
      #pragma unroll
      for (int j=0;j<4;++j){
        int ci = cg*4+j;
        f4_t vv = *reinterpret_cast<const f4_t*>(&Vm[((long)b*NM + c*64+ci)*768 + h*64 + eq*4]);
        f4_t dd = sLr[ci]*(acc[j] - vv);
        *reinterpret_cast<f4_t*>(&sD[ci*64 + eq*4]) = dd;
      }
    }
    __syncthreads();

    // ---- g2[d][e] = sum_ci G[ci][d]*D[ci][e]  -> overwrite G ----
    {
      f4_t acc[4] = {};
      #pragma unroll 4
      for (int ci=0; ci<64; ++ci){
        f4_t bv = *reinterpret_cast<const f4_t*>(&sD[ci*64 + eq*4]);
        #pragma unroll
        for (int j=0;j<4;++j) acc[j] += sG[ci*65 + cg*4 + j] * bv;
      }
      __syncthreads();
      #pragma unroll
      for (int j=0;j<4;++j)
        #pragma unroll
        for (int k=0;k<4;++k) sG[(cg*4+j)*65 + eq*4 + k] = acc[j][k];
    }
    __syncthreads();

    // ---- dg[ci][d] = (sum_e D[ci][e]*M2T[e][d]) * GP[ci][d]  -> overwrite D ----
    {
      f4_t acc[4] = {};
      #pragma unroll 4
      for (int e=0; e<64; ++e){
        f4_t bv = *reinterpret_cast<const f4_t*>(&sM2T[e*64 + eq*4]);
        #pragma unroll
        for (int j=0;j<4;++j) acc[j] += sD[(cg*4+j)*64 + e] * bv;
      }
      #pragma unroll
      for (int j=0;j<4;++j)
        acc[j] *= *reinterpret_cast<const f4_t*>(&sGP[(cg*4+j)*64 + eq*4]);
      __syncthreads();
      #pragma unroll
      for (int j=0;j<4;++j)
        *reinterpret_cast<f4_t*>(&sD[(cg*4+j)*64 + eq*4]) = acc[j];
    }
    __syncthreads();

    // ---- g1[d][e] = sum_ci K[ci][d]*dg[ci][e]  -> overwrite K ----
    {
      f4_t acc[4] = {};
      #pragma unroll 4
      for (int ci=0; ci<64; ++ci){
        f4_t bv = *reinterpret_cast<const f4_t*>(&sD[ci*64 + eq*4]);
        #pragma unroll
        for (int j=0;j<4;++j) acc[j] += sK[ci*65 + cg*4 + j] * bv;
      }
      __syncthreads();
      #pragma unroll
      for (int j=0;j<4;++j)
        #pragma unroll
        for (int k=0;k<4;++k) sK[(cg*4+j)*65 + eq*4 + k] = acc[j][k];
    }
    __syncthreads();

    specnorm_update(sK, sS1, sM1, momc, decc, sVec, sU, sred);
    specnorm_update(sG, sS2, sM2, momc, decc, sVec, sU, sred);

    // ---- out = gelu(Q @ M1) @ M2 ----
    for (int i=tid; i<1024; i+=256){
      int ci = i >> 4, q = i & 15;
      f4_t qv = *reinterpret_cast<const f4_t*>(&Qm[((long)b*NM + c*64+ci)*768 + h*64 + q*4]);
      #pragma unroll
      for (int k=0;k<4;++k) sK[ci*65 + q*4 + k] = qv[k];
    }
    __syncthreads();
    {
      f4_t acc[4] = {};
      #pragma unroll 4
      for (int d=0; d<64; ++d){
        f4_t bv = *reinterpret_cast<const f4_t*>(&sM1[d*64 + eq*4]);
        #pragma unroll
        for (int j=0;j<4;++j) acc[j] += sK[(cg*4+j)*65 + d] * bv;
      }
      #pragma unroll
      for (int j=0;j<4;++j)
        #pragma unroll
        for (int k=0;k<4;++k) sG[(cg*4+j)*65 + eq*4 + k] = gelu_f(acc[j][k]);
    }
    __syncthreads();
    {
      f4_t acc[4] = {};
      #pragma unroll 4
      for (int d=0; d<64; ++d){
        f4_t bv = *reinterpret_cast<const f4_t*>(&sM2[d*64 + eq*4]);
        #pragma unroll
        for (int j=0;j<4;++j) acc[j] += sG[(cg*4+j)*65 + d] * bv;
      }
      #pragma unroll
      for (int j=0;j<4;++j)
        *reinterpret_cast<f4_t*>(&OUT[((long)b*NM + c*64 + cg*4+j)*768 + h*64 + eq*4]) = acc[j];
    }
    __syncthreads();
  }
}

// ---------------- launch ----------------
extern "C" void kernel_launch(void* const* d_in, const int* in_sizes, int n_in,
                              void* d_out, int out_size, void* d_ws, size_t ws_size,
                              hipStream_t stream)
{
  const float* img = (const float*)d_in[0];
  const float* p1s = (const float*)d_in[1];
  const float* p1b = (const float*)d_in[2];
  const float* Wp  = (const float*)d_in[3];
  const float* bp  = (const float*)d_in[4];
  const float* p2s = (const float*)d_in[5];
  const float* p2b = (const float*)d_in[6];
  const float* cls = (const float*)d_in[7];
  const float* las = (const float*)d_in[8];
  const float* lab = (const float*)d_in[9];
  const float* Wqkv= (const float*)d_in[10];
  const float* Wao = (const float*)d_in[11];
  const float* regs= (const float*)d_in[12];
  const float* lms = (const float*)d_in[13];
  const float* lmb = (const float*)d_in[14];
  const float* Wmq = (const float*)d_in[15];
  const float* Wmk = (const float*)d_in[16];
  const float* Wmv = (const float*)d_in[17];
  const float* Wmo = (const float*)d_in[18];
  const float* Wlr = (const float*)d_in[19];
  const float* blr = (const float*)d_in[20];
  const float* Wmom= (const float*)d_in[21];
  const float* bmom= (const float*)d_in[22];
  const float* Wdec= (const float*)d_in[23];
  const float* bdec= (const float*)d_in[24];
  const float* M1i = (const float*)d_in[25];
  const float* M2i = (const float*)d_in[26];
  const float* fls = (const float*)d_in[27];
  const float* flb = (const float*)d_in[28];
  const float* Wh  = (const float*)d_in[29];
  const float* bh  = (const float*)d_in[30];
  float* out = (float*)d_out;

  float* ws = (float*)d_ws;
  size_t off = 0;
  auto alloc = [&](size_t n){ float* p = ws + off; off += n; return p; };
  float* XF   = alloc((size_t)B_*NTOK*768);
  float* XN_A = alloc((size_t)B_*NA*768);
  float* QKV  = alloc((size_t)B_*NA*2304);
  float* ATT_O= alloc((size_t)B_*NA*768);
  float* XN_M = alloc((size_t)B_*NM*768);
  float* QM   = alloc((size_t)B_*NM*768);
  float* KM   = alloc((size_t)B_*NM*768);
  float* VM   = alloc((size_t)B_*NM*768);
  float* LRb  = alloc((size_t)B_*NM*12);
  float* MOMb = alloc((size_t)B_*4*12);
  float* DECb = alloc((size_t)B_*4*12);
  float* MEMO = alloc((size_t)B_*NM*768);
  float* XHEAD= alloc((size_t)B_*768);
  float* XP = QKV;   // patch temps alias later buffers (disjoint lifetime)
  float* XE = XN_M;

  // patch embed
  patch_ln1_k<<<dim3(196,B_),256,0,stream>>>(img, p1s, p1b, XP);
  gemm_bf16_k<<<dim3(6,49,1),256,0,stream>>>(XP,0,768, Wp,768, bp, nullptr,0,0,
                                             XE,0,768, 6272,768,768);
  patch_final_k<<<dim3(197,B_),256,0,stream>>>(XE, p2s, p2b, cls, XF);

  for (int l=0; l<12; ++l){
    const float* Wqkv_l = Wqkv + (long)l*768*2304;
    const float* Wao_l  = Wao  + (long)l*768*768;
    const float* Wmq_l  = Wmq  + (long)l*768*768;
    const float* Wmk_l  = Wmk  + (long)l*768*768;
    const float* Wmv_l  = Wmv  + (long)l*768*768;
    const float* Wmo_l  = Wmo  + (long)l*768*768;
    const float* Wlr_l  = Wlr  + (long)l*768*12;
    const float* blr_l  = blr  + (long)l*12;
    const float* Wmom_l = Wmom + (long)l*768*12;
    const float* bmom_l = bmom + (long)l*12;
    const float* Wdec_l = Wdec + (long)l*768*12;
    const float* bdec_l = bdec + (long)l*12;

    // windowed attention
    ln_rows_k<<<dim3(NA,B_),256,0,stream>>>(XF,(long)NTOK*768,768, nullptr,
                                            las+l*768, lab+l*768,
                                            XN_A,(long)NA*768,768, NTOK, NTOK);
    gemm_bf16_k<<<dim3(18,53,1),256,0,stream>>>(XN_A,0,768, Wqkv_l,2304, nullptr, nullptr,0,0,
                                                QKV,0,2304, B_*NA,2304,768);
    win_attn_k<<<dim3(15,12,B_),256,0,stream>>>(QKV, ATT_O);
    gemm_bf16_k<<<dim3(6,2,B_),256,0,stream>>>(ATT_O,(long)NA*768,768, Wao_l,768, nullptr,
                                               XF,(long)NTOK*768,768,
                                               XF,(long)NTOK*768,768, NTOK,768,768);

    // neural memory
    ln_rows_k<<<dim3(NM,B_),256,0,stream>>>(XF,(long)NTOK*768,768, regs+(long)l*4*768,
                                            lms+l*768, lmb+l*768,
                                            XN_M,(long)NM*768,768, NTOK, NRM);
    gemm_bf16_k<<<dim3(6,64,1),256,0,stream>>>(XN_M,0,768, Wmq_l,768, nullptr, nullptr,0,0,
                                               QM,0,768, B_*NM,768,768);
    gemm_bf16_k<<<dim3(6,64,1),256,0,stream>>>(XN_M,0,768, Wmk_l,768, nullptr, nullptr,0,0,
                                               KM,0,768, B_*NM,768,768);
    gemm_bf16_k<<<dim3(6,64,1),256,0,stream>>>(XN_M,0,768, Wmv_l,768, nullptr, nullptr,0,0,
                                               VM,0,768, B_*NM,768,768);
    lr_k<<<dim3(NM,B_),256,0,stream>>>(XN_M, Wlr_l, blr_l, LRb);
    momdec_k<<<dim3(4,B_),256,0,stream>>>(XN_M, Wmom_l, bmom_l, Wdec_l, bdec_l, MOMb, DECb);
    memscan_k<<<dim3(12,B_),256,0,stream>>>(QM, KM, VM, LRb, MOMb, DECb,
                                            M1i+(long)l*4096, M2i+(long)l*4096, MEMO);
    gemm_bf16_k<<<dim3(6,2,B_),256,0,stream>>>(MEMO,(long)NM*768,768, Wmo_l,768, nullptr,
                                               XF,(long)NTOK*768,768,
                                               XF,(long)NTOK*768,768, NTOK,768,768);
  }

  // final LN (row 0 only) + head
  ln_rows_k<<<dim3(1,B_),256,0,stream>>>(XF,(long)NTOK*768,768, nullptr, fls, flb,
                                         XHEAD,768,768, 1, 1);
  gemm_k<<<dim3(16,1,1),256,0,stream>>>(XHEAD,0,768, Wh, bh, nullptr,0,0,
                                        out,0,1000, 32,1000,768);
}